// Round 10
// baseline (143.419 us; speedup 1.0000x reference)
//
#include <hip/hip_runtime.h>
#include <math.h>

#define CC 512
#define HH 38
#define WW 63
#define HWSZ (HH * WW)
#define NROIS 1024
#define NP 49              // 7x7 pooled positions

typedef float    f32x4 __attribute__((ext_vector_type(4)));
typedef _Float16 f16x8 __attribute__((ext_vector_type(8)));
typedef _Float16 f16x4 __attribute__((ext_vector_type(4)));

static __device__ __forceinline__ _Float16 lo_h(int v) {
    unsigned short u = (unsigned short)(v & 0xffff);
    return __builtin_bit_cast(_Float16, u);
}

// ------------- transpose + convert: CHW f32 (512,2394) -> HWC fp16 (2394,512)
__global__ __launch_bounds__(256) void transpose_cvt(
        const float* __restrict__ src, _Float16* __restrict__ dst) {
    __shared__ float tile[64][65];
    int s0 = blockIdx.x * 64;
    int c0 = blockIdx.y * 64;
    int tx = threadIdx.x & 63;
    int ty = threadIdx.x >> 6;

#pragma unroll
    for (int k = 0; k < 16; ++k) {
        int c = ty * 16 + k;
        int s = s0 + tx;
        float v = (s < HWSZ) ? src[(c0 + c) * HWSZ + s] : 0.0f;
        tile[tx][c] = v;
    }
    __syncthreads();

    // store phase: f16x4 (8B) stores -- 16 ch-quads x 16 row-groups of 4
    int u = threadIdx.x & 15;       // channel quad (4u..4u+3)
    int vv = threadIdx.x >> 4;      // row group
#pragma unroll
    for (int k = 0; k < 4; ++k) {
        int s = vv * 4 + k;
        if (s0 + s < HWSZ) {
            f16x4 h;
#pragma unroll
            for (int j = 0; j < 4; ++j) h[j] = (_Float16)tile[s][4 * u + j];
            *(f16x4*)(dst + (size_t)(s0 + s) * CC + c0 + 4 * u) = h;
        }
    }
}

// ---------------- main kernel v15 --------------------------------------------
// v14 skeleton (slot = sample row iy, LDS x-params, uniform-validity branch,
// 4-weight pk-FMA bilinear). v15 deletes the slot-pair shuffle epilogue:
// post-mortem showed the per-ox epilogue (4 init + 4 inv + 4 ds_swizzle +
// 4 pk_max + 8 v_cvt + 8 ds_write = 32 wave-instrs/ox) was the largest
// remaining removable class. Now BOTH parities write their f16 acc directly
// (8 ds_write_u16, no cvt, no shfl) into one of two f16 slabs that linearly
// mirror the output layout (stage_h[parity][c*49+p], 2 x 12544 B = same
// 25088 B LDS footprint). The sy-max moves to the flush, which is purely
// LINEAR elementwise (no channel structure, no div-by-49, 16B-aligned
// always): per 8 outputs read f16x8 from each slab, 4 pk_max, 8 cvt, 2
// nontemporal f32x4 stores. Net ~ -84 wave-instrs. Numerics bit-identical
// to v14 (same f16 max previously done by the shfl partner, same final
// cvt): absmax must stay exactly 0.015625.
__global__ __launch_bounds__(256) void roi_pool_v15(
        const _Float16* __restrict__ img,  // HWC fp16 (2394, 512)
        const float* __restrict__ rois,    // (N, 5)
        float* __restrict__ out) {         // (N, 512, 7, 7)
    __shared__ _Float16 stage_h[2][128 * NP];  // 2 x 12544 B, linear out-mirror
    __shared__ int4  xprm[14];             // {xo0, xo1, (mx<<16)|wx, vx}

    int n = blockIdx.x >> 2;              // wave-uniform
    int q = blockIdx.x & 3;
    int t = threadIdx.x;
    int g = t & 15;                       // channel oct within quarter
    int slot = t >> 4;                    // 0..15; slots 0..13 = sample row iy

    const float* r = rois + n * 5;
    float x1n = (r[1] * 0.0625f) / 62.0f;
    float y1n = (r[2] * 0.0625f) / 37.0f;
    float x2n = (r[3] * 0.0625f) / 62.0f;
    float y2n = (r[4] * 0.0625f) / 37.0f;
    float ydn = y2n - y1n;
    float xdn = x2n - x1n;

    // ---- per-block x-param precompute (threads 0..13, once) ----
    if (t < 14) {
        float A = x1n * 62.0f;
        float B = xdn * 62.0f;
        float ttx = (float)t * (1.0f / 13.0f);
        float in_x = fmaf(ttx, B, A);
        int vx = (in_x >= 0.0f && in_x <= 62.0f) ? 1 : 0;
        float x0f = floorf(in_x);
        _Float16 wxh = (_Float16)(in_x - x0f);
        _Float16 mxh = (_Float16)1.0f - wxh;
        int x0i = (int)fminf(fmaxf(x0f, 0.0f), 62.0f);
        int x1i = min(x0i + 1, 62);
        int wm = (int)__builtin_bit_cast(unsigned short, wxh)
               | ((int)__builtin_bit_cast(unsigned short, mxh) << 16);
        xprm[t] = make_int4(x0i << 9, x1i << 9, wm, vx);   // offsets in halfs
    }
    __syncthreads();

    if (slot < 14) {
        int iy = slot;
        int oy = iy >> 1;
        int par = iy & 1;                 // parity slab
        // this slot's y-params (one sample row)
        float tty = (float)iy * (1.0f / 13.0f);
        float in_y = (y1n + tty * ydn) * 37.0f;
        bool vy = (in_y >= 0.0f) && (in_y <= 37.0f);
        float y0f = floorf(in_y);
        _Float16 wyh = (_Float16)(in_y - y0f);
        _Float16 myh = (_Float16)1.0f - wyh;
        int yb0 = (int)fminf(fmaxf(y0f, 0.0f), 37.0f) * (WW * CC);        // halfs
        int yb1 = (int)fminf(fmaxf(y0f + 1.0f, 0.0f), 37.0f) * (WW * CC);

        int loff = (q << 7) + (g << 3);   // lane channel offset in halfs
        int b00 = loff + yb0;             // hoisted row bases
        int b10 = loff + yb1;

        _Float16* slab = stage_h[par];
        int sbase = (g * 8) * NP;         // channel-major half index base

#pragma unroll
        for (int ox = 0; ox < 7; ++ox) {
            f16x8 acc;
#pragma unroll
            for (int j = 0; j < 8; ++j) acc[j] = (_Float16)(-INFINITY);
            bool inv = false;

#pragma unroll
            for (int sx = 0; sx < 2; ++sx) {
                int ix = ox * 2 + sx;
                int4 xp = xprm[ix];       // one ds_read_b128, broadcast
                bool valid = vy && (xp.w != 0);
                if (valid) {
                    _Float16 wxh = lo_h(xp.z);
                    _Float16 mxh = lo_h(xp.z >> 16);

                    f16x8 g00 = *(const f16x8*)(img + (b00 + xp.x));
                    f16x8 g01 = *(const f16x8*)(img + (b00 + xp.y));
                    f16x8 g10 = *(const f16x8*)(img + (b10 + xp.x));
                    f16x8 g11 = *(const f16x8*)(img + (b10 + xp.y));

                    _Float16 w00 = mxh * myh;             // 4 corner weights
                    _Float16 w01 = wxh * myh;
                    _Float16 w10 = mxh * wyh;
                    _Float16 w11 = wxh * wyh;

                    f16x8 val = g00 * w00;                // v_pk_mul/fma
                    val = g01 * w01 + val;
                    val = g10 * w10 + val;
                    val = g11 * w11 + val;
                    acc = __builtin_elementwise_max(acc, val);
                } else {
                    inv = true;
                }
            }
            if (inv) {      // invalid samples contribute 0 to the max (rare)
                f16x8 z;
#pragma unroll
                for (int j = 0; j < 8; ++j) z[j] = (_Float16)0.0f;
                acc = __builtin_elementwise_max(acc, z);
            }

            // stage: 8 scalar f16 writes into this parity's output-mirror slab
            int pos = oy * 7 + ox;
#pragma unroll
            for (int j = 0; j < 8; ++j)
                slab[sbase + j * NP + pos] = acc[j];
        }
    }

    __syncthreads();

    // flush: LINEAR elementwise max of the two slabs + cvt + dense nt stores.
    // 784 f16x8 chunks -> 1568 f32x4 outputs for this quarter.
    const f16x8* e8 = (const f16x8*)stage_h[0];
    const f16x8* o8 = (const f16x8*)stage_h[1];
    f32x4* o4 = (f32x4*)(out + ((n << 9) + (q << 7)) * NP);
    for (int i = t; i < (128 * NP) / 8; i += 256) {
        f16x8 a = e8[i];
        f16x8 b = o8[i];
        f16x8 m = __builtin_elementwise_max(a, b);
        f32x4 lo, hi;
#pragma unroll
        for (int j = 0; j < 4; ++j) { lo[j] = (float)m[j]; hi[j] = (float)m[j + 4]; }
        __builtin_nontemporal_store(lo, &o4[2 * i]);
        __builtin_nontemporal_store(hi, &o4[2 * i + 1]);
    }
}

// ---------------- fallback (ws too small): direct CHW f32 gathers ------------
__global__ __launch_bounds__(256) void roi_pool_chw(
        const float* __restrict__ img,    // CHW
        const float* __restrict__ rois,
        float* __restrict__ out) {
    __shared__ float stage[256 * NP];
    int n = blockIdx.x >> 1;
    int h = blockIdx.x & 1;
    int t = threadIdx.x;
    int c = (h << 8) + t;

    const float* r = rois + n * 5;
    float x1n = (r[1] * 0.0625f) / 62.0f;
    float y1n = (r[2] * 0.0625f) / 37.0f;
    float x2n = (r[3] * 0.0625f) / 62.0f;
    float y2n = (r[4] * 0.0625f) / 37.0f;
    float ydn = y2n - y1n;
    float xdn = x2n - x1n;

    const float* imgc = img + c * HWSZ;

    float wxa[14];
    int   x0a[14], x1a[14];
    int   vxm = 0;
#pragma unroll
    for (int ix = 0; ix < 14; ++ix) {
        float tt = (float)ix * (1.0f / 13.0f);
        float in_x = (x1n + tt * xdn) * 62.0f;
        if (in_x >= 0.0f && in_x <= 62.0f) vxm |= (1 << ix);
        float x0f = floorf(in_x);
        wxa[ix] = in_x - x0f;
        x0a[ix] = (int)fminf(fmaxf(x0f, 0.0f), 62.0f);
        x1a[ix] = (int)fminf(fmaxf(x0f + 1.0f, 0.0f), 62.0f);
    }

#pragma unroll
    for (int oy = 0; oy < 7; ++oy) {
        float row[7];
#pragma unroll
        for (int ox = 0; ox < 7; ++ox) row[ox] = -INFINITY;
#pragma unroll
        for (int sy = 0; sy < 2; ++sy) {
            int iy = oy * 2 + sy;
            float tt = (float)iy * (1.0f / 13.0f);
            float in_y = (y1n + tt * ydn) * 37.0f;
            bool vy = (in_y >= 0.0f) && (in_y <= 37.0f);
            float y0f = floorf(in_y);
            float wy = in_y - y0f;
            int yy0 = (int)fminf(fmaxf(y0f, 0.0f), 37.0f);
            int yy1 = (int)fminf(fmaxf(y0f + 1.0f, 0.0f), 37.0f);
            int yb0 = yy0 * WW;
            int yb1 = yy1 * WW;
#pragma unroll
            for (int ox = 0; ox < 7; ++ox) {
#pragma unroll
                for (int sx = 0; sx < 2; ++sx) {
                    int ix = ox * 2 + sx;
                    float g00 = imgc[yb0 + x0a[ix]];
                    float g01 = imgc[yb0 + x1a[ix]];
                    float g10 = imgc[yb1 + x0a[ix]];
                    float g11 = imgc[yb1 + x1a[ix]];
                    float wx = wxa[ix];
                    float top = g00 + (g01 - g00) * wx;
                    float bot = g10 + (g11 - g10) * wx;
                    float val = top + (bot - top) * wy;
                    bool valid = vy && ((vxm >> ix) & 1);
                    val = valid ? val : 0.0f;
                    row[ox] = fmaxf(row[ox], val);
                }
            }
        }
#pragma unroll
        for (int ox = 0; ox < 7; ++ox)
            stage[t * NP + oy * 7 + ox] = row[ox];
    }

    __syncthreads();
    const float4* s4 = (const float4*)stage;
    float4* o4 = (float4*)(out + ((n << 9) + (h << 8)) * NP);
    for (int i = t; i < (256 * NP) / 4; i += 256)
        o4[i] = s4[i];
}

extern "C" void kernel_launch(void* const* d_in, const int* in_sizes, int n_in,
                              void* d_out, int out_size, void* d_ws, size_t ws_size,
                              hipStream_t stream) {
    const float* bottom = (const float*)d_in[0];
    const float* rois   = (const float*)d_in[1];
    float* out = (float*)d_out;

    const size_t need = (size_t)CC * HWSZ * sizeof(_Float16);  // ~2.45 MB
    if (ws_size >= need) {
        _Float16* img = (_Float16*)d_ws;
        dim3 tg((HWSZ + 63) / 64, CC / 64);   // 38 x 8
        transpose_cvt<<<tg, 256, 0, stream>>>(bottom, img);
        roi_pool_v15<<<NROIS * 4, 256, 0, stream>>>(img, rois, out);
    } else {
        roi_pool_chw<<<NROIS * 2, 256, 0, stream>>>(bottom, rois, out);
    }
}

// Round 11
// 138.037 us; speedup vs baseline: 1.0390x; 1.0390x over previous
//
#include <hip/hip_runtime.h>
#include <math.h>

#define CC 512
#define HH 38
#define WW 63
#define HWSZ (HH * WW)
#define NROIS 1024
#define NP 49              // 7x7 pooled positions

typedef float    f32x4 __attribute__((ext_vector_type(4)));
typedef _Float16 f16x8 __attribute__((ext_vector_type(8)));
typedef _Float16 f16x4 __attribute__((ext_vector_type(4)));

// ------------- transpose + convert: CHW f32 (512,2394) -> HWC fp16 (2394,512)
__global__ __launch_bounds__(256) void transpose_cvt(
        const float* __restrict__ src, _Float16* __restrict__ dst) {
    __shared__ float tile[64][65];
    int s0 = blockIdx.x * 64;
    int c0 = blockIdx.y * 64;
    int tx = threadIdx.x & 63;
    int ty = threadIdx.x >> 6;

#pragma unroll
    for (int k = 0; k < 16; ++k) {
        int c = ty * 16 + k;
        int s = s0 + tx;
        float v = (s < HWSZ) ? src[(c0 + c) * HWSZ + s] : 0.0f;
        tile[tx][c] = v;
    }
    __syncthreads();

    // store phase: f16x4 (8B) stores -- 16 ch-quads x 16 row-groups of 4
    int u = threadIdx.x & 15;       // channel quad (4u..4u+3)
    int vv = threadIdx.x >> 4;      // row group
#pragma unroll
    for (int k = 0; k < 4; ++k) {
        int s = vv * 4 + k;
        if (s0 + s < HWSZ) {
            f16x4 h;
#pragma unroll
            for (int j = 0; j < 4; ++j) h[j] = (_Float16)tile[s][4 * u + j];
            *(f16x4*)(dst + (size_t)(s0 + s) * CC + c0 + 4 * u) = h;
        }
    }
}

// ---------------- main kernel v16 == v13 (session best, 137.88 us) -----------
// REVERT: v14 (LDS x-param hoist) was null -- fully-unrolled loops mean the
// compiler had already hoisted loop-invariant x-math; v15 (slot-pair-shuffle
// deletion) regressed -- doubled LDS write traffic + doubled flush reads
// outweighed the removed shuffle. v13's structure stands as measured best:
//  - quarter-roi blocks (128 ch), lane g = channel oct, slot = sample row iy
//    (14 of 16 active), uniform-validity branch;
//  - fp16 HWC image (2.45 MB, L2-resident), f16x8 corner gathers (16B/lane);
//  - 4-weight packed-f16 bilinear (w = (1-wx,wx)x(1-wy,wy), 16 pk-FMA + 4
//    pk-max per output);
//  - sy-max via shfl_xor(16) across slot pairs (same wave);
//  - even slots convert + write f32 stage in output layout; pure linear
//    nontemporal float4 flush.
__global__ __launch_bounds__(256) void roi_pool_v16(
        const _Float16* __restrict__ img,  // HWC fp16 (2394, 512)
        const float* __restrict__ rois,    // (N, 5)
        float* __restrict__ out) {         // (N, 512, 7, 7)
    __shared__ float stage[128 * NP];      // 25088 B, output layout [c][p]

    int n = blockIdx.x >> 2;              // wave-uniform
    int q = blockIdx.x & 3;
    int t = threadIdx.x;
    int g = t & 15;                       // channel oct within quarter
    int slot = t >> 4;                    // 0..15; slots 0..13 = sample row iy

    const float* r = rois + n * 5;
    float x1n = (r[1] * 0.0625f) / 62.0f;
    float y1n = (r[2] * 0.0625f) / 37.0f;
    float x2n = (r[3] * 0.0625f) / 62.0f;
    float y2n = (r[4] * 0.0625f) / 37.0f;
    float ydn = y2n - y1n;
    float xdn = x2n - x1n;

    // hoisted x-line coefficients: in_x = A + ttx * B
    float A = x1n * 62.0f;
    float B = xdn * 62.0f;

    if (slot < 14) {
        int iy = slot;
        int oy = iy >> 1;
        // this slot's y-params (one sample row)
        float tty = (float)iy * (1.0f / 13.0f);
        float in_y = (y1n + tty * ydn) * 37.0f;
        bool vy = (in_y >= 0.0f) && (in_y <= 37.0f);
        float y0f = floorf(in_y);
        _Float16 wyh = (_Float16)(in_y - y0f);
        _Float16 myh = (_Float16)1.0f - wyh;
        int yb0 = (int)fminf(fmaxf(y0f, 0.0f), 37.0f) * (WW * CC);        // halfs
        int yb1 = (int)fminf(fmaxf(y0f + 1.0f, 0.0f), 37.0f) * (WW * CC);

        const _Float16* imgc = img + (q << 7) + (g << 3);   // +q*128 +8g halfs

#pragma unroll
        for (int ox = 0; ox < 7; ++ox) {
            f16x8 acc;
#pragma unroll
            for (int j = 0; j < 8; ++j) acc[j] = (_Float16)(-INFINITY);
            bool inv = false;

#pragma unroll
            for (int sx = 0; sx < 2; ++sx) {
                int ix = ox * 2 + sx;
                float ttx = (float)ix * (1.0f / 13.0f);
                float in_x = fmaf(ttx, B, A);
                bool valid = vy && (in_x >= 0.0f) && (in_x <= 62.0f);
                if (valid) {
                    float x0f = floorf(in_x);
                    _Float16 wxh = (_Float16)(in_x - x0f);
                    _Float16 mxh = (_Float16)1.0f - wxh;
                    int x0i = (int)x0f;                   // in [0,62], no clamp
                    int x1i = min(x0i + 1, 62);
                    int xo0 = x0i << 9;                   // * CC halfs
                    int xo1 = x1i << 9;

                    f16x8 g00 = *(const f16x8*)(imgc + yb0 + xo0);
                    f16x8 g01 = *(const f16x8*)(imgc + yb0 + xo1);
                    f16x8 g10 = *(const f16x8*)(imgc + yb1 + xo0);
                    f16x8 g11 = *(const f16x8*)(imgc + yb1 + xo1);

                    _Float16 w00 = mxh * myh;             // 4 corner weights
                    _Float16 w01 = wxh * myh;
                    _Float16 w10 = mxh * wyh;
                    _Float16 w11 = wxh * wyh;

                    f16x8 val = g00 * w00;                // 4x v_pk_mul/fma
                    val = g01 * w01 + val;
                    val = g10 * w10 + val;
                    val = g11 * w11 + val;
                    acc = __builtin_elementwise_max(acc, val);
                } else {
                    inv = true;
                }
            }
            if (inv) {      // invalid samples contribute 0 to the max (rare)
                f16x8 z;
#pragma unroll
                for (int j = 0; j < 8; ++j) z[j] = (_Float16)0.0f;
                acc = __builtin_elementwise_max(acc, z);
            }

            // sy-max across the slot pair: lanes l <-> l^16, 4 dwords only
            int4 ai = __builtin_bit_cast(int4, acc);
            ai.x = __shfl_xor(ai.x, 16);
            ai.y = __shfl_xor(ai.y, 16);
            ai.z = __shfl_xor(ai.z, 16);
            ai.w = __shfl_xor(ai.w, 16);
            f16x8 other = __builtin_bit_cast(f16x8, ai);
            acc = __builtin_elementwise_max(acc, other);

            if (!(slot & 1)) {   // even slot converts + writes final outputs
                int pos = oy * 7 + ox;
#pragma unroll
                for (int j = 0; j < 8; ++j)
                    stage[(g * 8 + j) * NP + pos] = (float)acc[j];
            }
        }
    }

    __syncthreads();

    // pure linear flush: stage layout == output layout for this quarter.
    const f32x4* s4 = (const f32x4*)stage;
    f32x4* o4 = (f32x4*)(out + ((n << 9) + (q << 7)) * NP);
    for (int i = t; i < (128 * NP) / 4; i += 256)
        __builtin_nontemporal_store(s4[i], &o4[i]);
}

// ---------------- fallback (ws too small): direct CHW f32 gathers ------------
__global__ __launch_bounds__(256) void roi_pool_chw(
        const float* __restrict__ img,    // CHW
        const float* __restrict__ rois,
        float* __restrict__ out) {
    __shared__ float stage[256 * NP];
    int n = blockIdx.x >> 1;
    int h = blockIdx.x & 1;
    int t = threadIdx.x;
    int c = (h << 8) + t;

    const float* r = rois + n * 5;
    float x1n = (r[1] * 0.0625f) / 62.0f;
    float y1n = (r[2] * 0.0625f) / 37.0f;
    float x2n = (r[3] * 0.0625f) / 62.0f;
    float y2n = (r[4] * 0.0625f) / 37.0f;
    float ydn = y2n - y1n;
    float xdn = x2n - x1n;

    const float* imgc = img + c * HWSZ;

    float wxa[14];
    int   x0a[14], x1a[14];
    int   vxm = 0;
#pragma unroll
    for (int ix = 0; ix < 14; ++ix) {
        float tt = (float)ix * (1.0f / 13.0f);
        float in_x = (x1n + tt * xdn) * 62.0f;
        if (in_x >= 0.0f && in_x <= 62.0f) vxm |= (1 << ix);
        float x0f = floorf(in_x);
        wxa[ix] = in_x - x0f;
        x0a[ix] = (int)fminf(fmaxf(x0f, 0.0f), 62.0f);
        x1a[ix] = (int)fminf(fmaxf(x0f + 1.0f, 0.0f), 62.0f);
    }

#pragma unroll
    for (int oy = 0; oy < 7; ++oy) {
        float row[7];
#pragma unroll
        for (int ox = 0; ox < 7; ++ox) row[ox] = -INFINITY;
#pragma unroll
        for (int sy = 0; sy < 2; ++sy) {
            int iy = oy * 2 + sy;
            float tt = (float)iy * (1.0f / 13.0f);
            float in_y = (y1n + tt * ydn) * 37.0f;
            bool vy = (in_y >= 0.0f) && (in_y <= 37.0f);
            float y0f = floorf(in_y);
            float wy = in_y - y0f;
            int yy0 = (int)fminf(fmaxf(y0f, 0.0f), 37.0f);
            int yy1 = (int)fminf(fmaxf(y0f + 1.0f, 0.0f), 37.0f);
            int yb0 = yy0 * WW;
            int yb1 = yy1 * WW;
#pragma unroll
            for (int ox = 0; ox < 7; ++ox) {
#pragma unroll
                for (int sx = 0; sx < 2; ++sx) {
                    int ix = ox * 2 + sx;
                    float g00 = imgc[yb0 + x0a[ix]];
                    float g01 = imgc[yb0 + x1a[ix]];
                    float g10 = imgc[yb1 + x0a[ix]];
                    float g11 = imgc[yb1 + x1a[ix]];
                    float wx = wxa[ix];
                    float top = g00 + (g01 - g00) * wx;
                    float bot = g10 + (g11 - g10) * wx;
                    float val = top + (bot - top) * wy;
                    bool valid = vy && ((vxm >> ix) & 1);
                    val = valid ? val : 0.0f;
                    row[ox] = fmaxf(row[ox], val);
                }
            }
        }
#pragma unroll
        for (int ox = 0; ox < 7; ++ox)
            stage[t * NP + oy * 7 + ox] = row[ox];
    }

    __syncthreads();
    const float4* s4 = (const float4*)stage;
    float4* o4 = (float4*)(out + ((n << 9) + (h << 8)) * NP);
    for (int i = t; i < (256 * NP) / 4; i += 256)
        o4[i] = s4[i];
}

extern "C" void kernel_launch(void* const* d_in, const int* in_sizes, int n_in,
                              void* d_out, int out_size, void* d_ws, size_t ws_size,
                              hipStream_t stream) {
    const float* bottom = (const float*)d_in[0];
    const float* rois   = (const float*)d_in[1];
    float* out = (float*)d_out;

    const size_t need = (size_t)CC * HWSZ * sizeof(_Float16);  // ~2.45 MB
    if (ws_size >= need) {
        _Float16* img = (_Float16*)d_ws;
        dim3 tg((HWSZ + 63) / 64, CC / 64);   // 38 x 8
        transpose_cvt<<<tg, 256, 0, stream>>>(bottom, img);
        roi_pool_v16<<<NROIS * 4, 256, 0, stream>>>(img, rois, out);
    } else {
        roi_pool_chw<<<NROIS * 2, 256, 0, stream>>>(bottom, rois, out);
    }
}